// Round 1
// baseline (35.947 us; speedup 1.0000x reference)
//
#include <hip/hip_runtime.h>
#include <math.h>

namespace {
constexpr int B = 8, N = 1024, Q = 128, K = 16, M = N + Q;   // M = 1152
constexpr int WAVES_PER_BLOCK = 4;
constexpr int NWAVES = B * M;                     // 9216
constexpr int NBLOCKS = NWAVES / WAVES_PER_BLOCK; // 2304
}

#if __has_builtin(__builtin_amdgcn_exp2f)
  #define EXP2F(x) __builtin_amdgcn_exp2f(x)
#else
  #define EXP2F(x) exp2f(x)
#endif

// ---------------------------------------------------------------------------
// Prep: per-kernel fused constants.
//   kern = exp(-(dx2*s0 + dy2*s1) / (tr * 2*bw^2))
//        = exp2(dx2*cA_k + dy2*cB_k)
//   cA_k = -s0*log2(e)/(tr*2bw^2),  cB_k = -s1*log2(e)/(tr*2bw^2)
// ---------------------------------------------------------------------------
__global__ void IvySPT_prep(const float* __restrict__ lsk, float* __restrict__ cc) {
  int k = threadIdx.x;
  if (k < K) {
    float s0 = expf(lsk[2 * k + 0]);
    float s1 = expf(lsk[2 * k + 1]);
    float tr = s0 + s1;
    float x  = (float)(k + 1) / (float)(K + 1);
    float bw = erfinvf(x) * 1.41421356237309504880f;
    float denom = tr * 2.0f * bw * bw;
    const float LOG2E = 1.44269504088896340736f;
    cc[k]     = -s0 * LOG2E / denom;
    cc[K + k] = -s1 * LOG2E / denom;
  }
}

// ---------------------------------------------------------------------------
// Main: one wave per (b, m) output row.
// ---------------------------------------------------------------------------
__global__ __launch_bounds__(256) void IvySPT_main(
    const float* __restrict__ lm_s, const float* __restrict__ ttm_s,
    const float* __restrict__ tv_s, const float* __restrict__ lm_q,
    const float* __restrict__ ttm_q,
    const float* __restrict__ ln_s_w, const float* __restrict__ ln_s_b,
    const float* __restrict__ ln_q_w, const float* __restrict__ ln_q_b,
    const float* __restrict__ pls_p, const float* __restrict__ cc,
    float* __restrict__ out)
{
  const int lane = threadIdx.x & 63;
  const int wid  = threadIdx.x >> 6;
  const int w    = blockIdx.x * WAVES_PER_BLOCK + wid;   // 0 .. 9215
  const int b    = w / M;
  const int m    = w - b * M;

  // this row's coordinates (wave-uniform)
  float cmx, cmy;
  if (m < N) { cmx = lm_s[b * N + m];       cmy = ttm_s[b * N + m]; }
  else       { cmx = lm_q[b * Q + (m - N)]; cmy = ttm_q[b * Q + (m - N)]; }

  // fused per-k constants (uniform -> scalar loads)
  float cA[K], cB[K];
#pragma unroll
  for (int k = 0; k < K; k++) { cA[k] = cc[k]; cB[k] = cc[K + k]; }

  float wsum[K], nrm[K];
#pragma unroll
  for (int k = 0; k < K; k++) { wsum[k] = 0.f; nrm[k] = 0.f; }

  const float* xs = lm_s  + b * N;
  const float* ys = ttm_s + b * N;
  const float* tv = tv_s  + b * N;

#pragma unroll 4
  for (int i = 0; i < N / 64; i++) {
    const int n = lane + 64 * i;
    float sx = xs[n], sy = ys[n], t = tv[n];
    float dx = cmx - sx, dy = cmy - sy;
    float dx2 = dx * dx, dy2 = dy * dy;
#pragma unroll
    for (int k = 0; k < K; k++) {
      float e = EXP2F(fmaf(dy2, cB[k], dx2 * cA[k]));
      wsum[k] = fmaf(e, t, wsum[k]);
      nrm[k] += e;
    }
  }

  // -------------------------------------------------------------------------
  // Wave-local reduction: LDS transpose [64][17] (pad -> only 2-way bank
  // aliasing, which is free), two passes. No __syncthreads needed: each wave
  // uses its own slab; DS ops are per-wave in-order, waitcnt orders lanes.
  // -------------------------------------------------------------------------
  __shared__ float red[WAVES_PER_BLOCK][64][17];
  float (*rp)[17] = red[wid];
  const int col = lane & 15;
  const int qq  = lane >> 4;

  float totW, totN;
  {
#pragma unroll
    for (int c = 0; c < K; c++) rp[lane][c] = wsum[c];
    asm volatile("s_waitcnt lgkmcnt(0)" ::: "memory");
    float s = 0.f;
#pragma unroll
    for (int r = 0; r < 16; r++) s += rp[qq * 16 + r][col];
    asm volatile("s_waitcnt lgkmcnt(0)" ::: "memory");  // reads drained before reuse
    s += __shfl_xor(s, 16);
    s += __shfl_xor(s, 32);
    totW = s;
  }
  {
#pragma unroll
    for (int c = 0; c < K; c++) rp[lane][c] = nrm[c];
    asm volatile("s_waitcnt lgkmcnt(0)" ::: "memory");
    float s = 0.f;
#pragma unroll
    for (int r = 0; r < 16; r++) s += rp[qq * 16 + r][col];
    s += __shfl_xor(s, 16);
    s += __shfl_xor(s, 32);
    totN = s;
  }

  // Every lane now holds totals for k = lane & 15.
  float emb = totW / totN;

  // LayerNorm over K=16 within each 16-lane group
  float s1 = emb;
  s1 += __shfl_xor(s1, 1); s1 += __shfl_xor(s1, 2);
  s1 += __shfl_xor(s1, 4); s1 += __shfl_xor(s1, 8);
  float mean = s1 * (1.f / 16.f);
  float dv = emb - mean;
  float s2 = dv * dv;
  s2 += __shfl_xor(s2, 1); s2 += __shfl_xor(s2, 2);
  s2 += __shfl_xor(s2, 4); s2 += __shfl_xor(s2, 8);
  float inv = rsqrtf(s2 * (1.f / 16.f) + 1e-5f);

  const int k = col;
  float lw, lb;
  if (m < N) { lw = ln_s_w[k]; lb = ln_s_b[k]; }
  else       { lw = ln_q_w[k]; lb = ln_q_b[k]; }
  float normed = dv * inv * lw + lb;

  // Positional embedding: k = 4*i + c; c<2 -> x else y; c odd -> cos.
  // x/div_i = x * exp(-pe_log_scale * i/4)
  float pls = pls_p[0];
  float invdiv = expf(-pls * (float)(k >> 2) * 0.25f);
  float cv  = (k & 2) ? cmy : cmx;
  float arg = cv * invdiv;
  float pe  = (k & 1) ? cosf(arg) : sinf(arg);
  float val = fmaf(pe, 1.41421356237309504880f, normed);

  if (lane < 16) out[((size_t)(b * M + m)) * K + k] = val;
}

extern "C" void kernel_launch(void* const* d_in, const int* in_sizes, int n_in,
                              void* d_out, int out_size, void* d_ws, size_t ws_size,
                              hipStream_t stream) {
  const float* lm_s   = (const float*)d_in[0];
  const float* ttm_s  = (const float*)d_in[1];
  const float* tv_s   = (const float*)d_in[2];
  const float* lm_q   = (const float*)d_in[3];
  const float* ttm_q  = (const float*)d_in[4];
  const float* lsk    = (const float*)d_in[5];
  const float* ln_s_w = (const float*)d_in[6];
  const float* ln_s_b = (const float*)d_in[7];
  const float* ln_q_w = (const float*)d_in[8];
  const float* ln_q_b = (const float*)d_in[9];
  const float* pls    = (const float*)d_in[10];

  float* cc  = (float*)d_ws;   // cA[16] ++ cB[16]
  float* out = (float*)d_out;

  hipLaunchKernelGGL(IvySPT_prep, dim3(1), dim3(64), 0, stream, lsk, cc);
  hipLaunchKernelGGL(IvySPT_main, dim3(NBLOCKS), dim3(256), 0, stream,
                     lm_s, ttm_s, tv_s, lm_q, ttm_q,
                     ln_s_w, ln_s_b, ln_q_w, ln_q_b, pls, cc, out);
}

// Round 2
// 30.093 us; speedup vs baseline: 1.1945x; 1.1945x over previous
//
#include <hip/hip_runtime.h>
#include <math.h>

namespace {
constexpr int B = 8, N = 1024, Q = 128, K = 16, M = N + Q;   // M = 1152
constexpr int WAVES_PER_BLOCK = 4;
constexpr int NWAVES = B * M;                     // 9216
constexpr int NBLOCKS = NWAVES / WAVES_PER_BLOCK; // 2304
typedef float f32x2 __attribute__((ext_vector_type(2)));
}

#if __has_builtin(__builtin_amdgcn_exp2f)
  #define EXP2F(x) __builtin_amdgcn_exp2f(x)
#else
  #define EXP2F(x) exp2f(x)
#endif

#if __has_builtin(__builtin_elementwise_fma)
  #define VFMA2(a, b, c) __builtin_elementwise_fma((a), (b), (c))
#else
  #define VFMA2(a, b, c) ((a) * (b) + (c))
#endif

// ---------------------------------------------------------------------------
// One kernel. Threads 0-15 compute the fused per-kernel constants into LDS:
//   kern = exp(-(dx2*s0 + dy2*s1) / (tr * 2*bw^2)) = exp2(dx2*cA_k + dy2*cB_k)
// Then one wave per (b, m) output row.
// ---------------------------------------------------------------------------
__global__ __launch_bounds__(256) void IvySPT_main(
    const float* __restrict__ lm_s, const float* __restrict__ ttm_s,
    const float* __restrict__ tv_s, const float* __restrict__ lm_q,
    const float* __restrict__ ttm_q, const float* __restrict__ lsk,
    const float* __restrict__ ln_s_w, const float* __restrict__ ln_s_b,
    const float* __restrict__ ln_q_w, const float* __restrict__ ln_q_b,
    const float* __restrict__ pls_p,
    float* __restrict__ out)
{
  __shared__ float sC[2][K];
  if (threadIdx.x < K) {
    const int k = threadIdx.x;
    float s0 = expf(lsk[2 * k + 0]);
    float s1 = expf(lsk[2 * k + 1]);
    float tr = s0 + s1;
    float x  = (float)(k + 1) / (float)(K + 1);
    float bw = erfinvf(x) * 1.41421356237309504880f;
    float denom = tr * 2.0f * bw * bw;
    const float LOG2E = 1.44269504088896340736f;
    sC[0][k] = -s0 * LOG2E / denom;
    sC[1][k] = -s1 * LOG2E / denom;
  }
  __syncthreads();

  const int lane = threadIdx.x & 63;
  const int wid  = threadIdx.x >> 6;
  const int w    = blockIdx.x * WAVES_PER_BLOCK + wid;   // 0 .. 9215
  const int b    = w / M;
  const int m    = w - b * M;

  // this row's coordinates (wave-uniform)
  float cmx, cmy;
  if (m < N) { cmx = lm_s[b * N + m];       cmy = ttm_s[b * N + m]; }
  else       { cmx = lm_q[b * Q + (m - N)]; cmy = ttm_q[b * Q + (m - N)]; }

  // fused per-k constants as packed pairs (LDS broadcast reads)
  f32x2 cA2[K / 2], cB2[K / 2];
#pragma unroll
  for (int j = 0; j < K / 2; j++) {
    cA2[j] = f32x2{sC[0][2 * j], sC[0][2 * j + 1]};
    cB2[j] = f32x2{sC[1][2 * j], sC[1][2 * j + 1]};
  }

  float wsum[K], nrm[K];
#pragma unroll
  for (int k = 0; k < K; k++) { wsum[k] = 0.f; nrm[k] = 0.f; }

  const float* xs = lm_s  + b * N;
  const float* ys = ttm_s + b * N;
  const float* tv = tv_s  + b * N;

#pragma unroll 2
  for (int i = 0; i < N / 64; i++) {
    const int n = lane + 64 * i;
    float sx = xs[n], sy = ys[n], t = tv[n];
    float dx = cmx - sx, dy = cmy - sy;
    float dx2 = dx * dx, dy2 = dy * dy;
    f32x2 dx2v = {dx2, dx2};
    f32x2 dy2v = {dy2, dy2};
#pragma unroll
    for (int j = 0; j < K / 2; j++) {
      f32x2 arg = VFMA2(dy2v, cB2[j], dx2v * cA2[j]);  // v_pk_mul + v_pk_fma
      float e0 = EXP2F(arg.x);
      float e1 = EXP2F(arg.y);
      wsum[2 * j]     = fmaf(e0, t, wsum[2 * j]);     nrm[2 * j]     += e0;
      wsum[2 * j + 1] = fmaf(e1, t, wsum[2 * j + 1]); nrm[2 * j + 1] += e1;
    }
  }

  // -------------------------------------------------------------------------
  // Wave-local reduction: LDS transpose [64][17] (pad -> only 2-way bank
  // aliasing, free), two passes. Per-wave slab; same-wave LDS ops are
  // ordered, explicit waitcnts are belt-and-braces.
  // -------------------------------------------------------------------------
  __shared__ float red[WAVES_PER_BLOCK][64][17];
  float (*rp)[17] = red[wid];
  const int col = lane & 15;
  const int qq  = lane >> 4;

  float totW, totN;
  {
#pragma unroll
    for (int c = 0; c < K; c++) rp[lane][c] = wsum[c];
    asm volatile("s_waitcnt lgkmcnt(0)" ::: "memory");
    float s = 0.f;
#pragma unroll
    for (int r = 0; r < 16; r++) s += rp[qq * 16 + r][col];
    asm volatile("s_waitcnt lgkmcnt(0)" ::: "memory");
    s += __shfl_xor(s, 16);
    s += __shfl_xor(s, 32);
    totW = s;
  }
  {
#pragma unroll
    for (int c = 0; c < K; c++) rp[lane][c] = nrm[c];
    asm volatile("s_waitcnt lgkmcnt(0)" ::: "memory");
    float s = 0.f;
#pragma unroll
    for (int r = 0; r < 16; r++) s += rp[qq * 16 + r][col];
    s += __shfl_xor(s, 16);
    s += __shfl_xor(s, 32);
    totN = s;
  }

  // Every lane now holds totals for k = lane & 15.
  float emb = totW / totN;

  // LayerNorm over K=16 within each 16-lane group
  float s1 = emb;
  s1 += __shfl_xor(s1, 1); s1 += __shfl_xor(s1, 2);
  s1 += __shfl_xor(s1, 4); s1 += __shfl_xor(s1, 8);
  float mean = s1 * (1.f / 16.f);
  float dv = emb - mean;
  float s2 = dv * dv;
  s2 += __shfl_xor(s2, 1); s2 += __shfl_xor(s2, 2);
  s2 += __shfl_xor(s2, 4); s2 += __shfl_xor(s2, 8);
  float inv = rsqrtf(s2 * (1.f / 16.f) + 1e-5f);

  const int k = col;
  float lw, lb;
  if (m < N) { lw = ln_s_w[k]; lb = ln_s_b[k]; }
  else       { lw = ln_q_w[k]; lb = ln_q_b[k]; }
  float normed = dv * inv * lw + lb;

  // Positional embedding: k = 4*i + c; c<2 -> x else y; c odd -> cos.
  float pls = pls_p[0];
  float invdiv = expf(-pls * (float)(k >> 2) * 0.25f);
  float cv  = (k & 2) ? cmy : cmx;
  float arg = cv * invdiv;
  float pe  = (k & 1) ? cosf(arg) : sinf(arg);
  float val = fmaf(pe, 1.41421356237309504880f, normed);

  if (lane < 16) out[((size_t)(b * M + m)) * K + k] = val;
}

extern "C" void kernel_launch(void* const* d_in, const int* in_sizes, int n_in,
                              void* d_out, int out_size, void* d_ws, size_t ws_size,
                              hipStream_t stream) {
  const float* lm_s   = (const float*)d_in[0];
  const float* ttm_s  = (const float*)d_in[1];
  const float* tv_s   = (const float*)d_in[2];
  const float* lm_q   = (const float*)d_in[3];
  const float* ttm_q  = (const float*)d_in[4];
  const float* lsk    = (const float*)d_in[5];
  const float* ln_s_w = (const float*)d_in[6];
  const float* ln_s_b = (const float*)d_in[7];
  const float* ln_q_w = (const float*)d_in[8];
  const float* ln_q_b = (const float*)d_in[9];
  const float* pls    = (const float*)d_in[10];

  float* out = (float*)d_out;

  hipLaunchKernelGGL(IvySPT_main, dim3(NBLOCKS), dim3(256), 0, stream,
                     lm_s, ttm_s, tv_s, lm_q, ttm_q, lsk,
                     ln_s_w, ln_s_b, ln_q_w, ln_q_b, pls, out);
}